// Round 1
// baseline (93.488 us; speedup 1.0000x reference)
//
#include <hip/hip_runtime.h>
#include <math.h>

#define BT    8192      // B*T = 16*512
#define IDIM  80
#define HDIM  512
#define SPAN  159       // 2*IDIM-1
#define PADX  320       // padded x buffer (zeros outside [79,158])
#define LDK   104       // LDS row stride in halfwords (bank-friendly, 16B-aligned)
#define RPB   32        // rows per block
#define NBLK  (BT / RPB)   // 256 blocks = 1 per CU

typedef unsigned short ushort_t;
typedef __attribute__((ext_vector_type(8))) short short8;
typedef __attribute__((ext_vector_type(4))) float floatx4;
typedef __attribute__((ext_vector_type(4))) unsigned short ushort4v;

__device__ inline ushort_t f2bf(float f) {
    union { float f; unsigned int i; } v; v.f = f;
    unsigned int x = v.i;
    return (ushort_t)((x + 0x7fffu + ((x >> 16) & 1u)) >> 16);   // RNE
}

__device__ inline float rlane(float v, int l) {
    return __uint_as_float((unsigned int)__builtin_amdgcn_readlane((int)__float_as_uint(v), l));
}

// ---------------- Fused kernel: attn + GEMM, no global workspace ----------------
// 256 blocks x 512 thr (8 waves). Block owns 32 rows x all 512 cols.
// Phase A: wave w computes attn for rows w*4..w*4+3 (x/y preloaded to regs),
//          writes bf16 x_attn directly into LDS A-tile.
// Phase B: stage W (fp32->bf16) into LDS (aliased over phase-A scratch),
//          then proven 16x16x32 bf16 MFMA tile + bias epilogue.
__global__ __launch_bounds__(512, 1) void k_fused(const float* __restrict__ x,
                                                  const float* __restrict__ y,
                                                  const float* __restrict__ wmat,
                                                  const float* __restrict__ bias,
                                                  float* __restrict__ out) {
    // Wbf: 512*104*2 = 106496 B. Abf: 32*104*2 = 6656 B. Total 113152 B (<160 KiB).
    __shared__ __align__(16) ushort_t Wbf[HDIM][LDK];
    __shared__ __align__(16) ushort_t Abf[RPB][LDK];

    const int tid  = threadIdx.x;
    const int wv   = tid >> 6;          // wave 0..7
    const int lane = tid & 63;
    const int rb   = blockIdx.x * RPB;

    // Phase-A scratch aliases the (not-yet-used) Wbf region:
    // xp[8][320] floats (10240 B) + ysm[8][80] floats (2560 B) = 12.8 KB
    float* scratch = (float*)(void*)&Wbf[0][0];
    float* xpw = scratch + wv * PADX;
    float* ysw = scratch + 8 * PADX + wv * IDIM;

    // zero this wave's padded-x buffer once (middle is rewritten per row)
    for (int j = lane; j < PADX; j += 64) xpw[j] = 0.f;

    // prefetch all 4 rows of x,y for this wave into registers (hide HBM latency)
    float4 xbuf[4], ybuf[4];
    #pragma unroll
    for (int r = 0; r < 4; ++r) {
        const int row = rb + wv * 4 + r;
        if (lane < 20) {
            xbuf[r] = *(const float4*)(x + (size_t)row * IDIM + lane * 4);
            ybuf[r] = *(const float4*)(y + (size_t)row * IDIM + lane * 4);
        }
    }

    // ---------------- Phase A: attention, 4 rows per wave ----------------
    for (int r = 0; r < 4; ++r) {
        const int lrow = wv * 4 + r;
        float4 yv4 = ybuf[r];
        float yy = 0.f;
        if (lane < 20) {
            float4 xv = xbuf[r];
            int b = 79 + lane * 4;
            xpw[b + 0] = xv.x; xpw[b + 1] = xv.y;
            xpw[b + 2] = xv.z; xpw[b + 3] = xv.w;
            int c = lane * 4;
            ysw[c + 0] = yv4.x; ysw[c + 1] = yv4.y;
            ysw[c + 2] = yv4.z; ysw[c + 3] = yv4.w;
            yy = yv4.x * yv4.x + yv4.y * yv4.y + yv4.z * yv4.z + yv4.w * yv4.w;
        }
        __syncthreads();
        #pragma unroll
        for (int off = 32; off; off >>= 1) yy += __shfl_xor(yy, off);

        // sliding dot + norm; y broadcast via v_readlane (keeps LDS pipe for xp)
        float d0 = 0.f, d1 = 0.f, d2 = 0.f, n0 = 0.f, n1 = 0.f, n2 = 0.f;
        #pragma unroll 4
        for (int i4 = 0; i4 < 20; ++i4) {
            float yv0 = rlane(yv4.x, i4);
            float yv1 = rlane(yv4.y, i4);
            float yv2 = rlane(yv4.z, i4);
            float yv3 = rlane(yv4.w, i4);
            const float* p = xpw + lane + i4 * 4;
            float a00 = p[0],   a01 = p[1],   a02 = p[2],   a03 = p[3];
            float a10 = p[64],  a11 = p[65],  a12 = p[66],  a13 = p[67];
            float a20 = p[128], a21 = p[129], a22 = p[130], a23 = p[131];
            d0 = fmaf(yv3, a03, fmaf(yv2, a02, fmaf(yv1, a01, fmaf(yv0, a00, d0))));
            n0 = fmaf(a03, a03, fmaf(a02, a02, fmaf(a01, a01, fmaf(a00, a00, n0))));
            d1 = fmaf(yv3, a13, fmaf(yv2, a12, fmaf(yv1, a11, fmaf(yv0, a10, d1))));
            n1 = fmaf(a13, a13, fmaf(a12, a12, fmaf(a11, a11, fmaf(a10, a10, n1))));
            d2 = fmaf(yv3, a23, fmaf(yv2, a22, fmaf(yv1, a21, fmaf(yv0, a20, d2))));
            n2 = fmaf(a23, a23, fmaf(a22, a22, fmaf(a21, a21, fmaf(a20, a20, n2))));
        }
        float s0 = (n0 > 0.f) ? d0 / sqrtf(yy * n0) : 0.f;
        float s1 = (n1 > 0.f) ? d1 / sqrtf(yy * n1) : 0.f;
        float s2 = (lane < 31) ? ((n2 > 0.f) ? d2 / sqrtf(yy * n2) : 0.f) : -INFINITY;

        // argmax, smallest index on ties (np.argmax semantics)
        float bv = s0; int bi = lane;
        if (s1 > bv) { bv = s1; bi = lane + 64; }
        if (s2 > bv) { bv = s2; bi = lane + 128; }
        #pragma unroll
        for (int off = 32; off; off >>= 1) {
            float ov = __shfl_xor(bv, off);
            int   oi = __shfl_xor(bi, off);
            if (ov > bv || (ov == bv && oi < bi)) { bv = ov; bi = oi; }
        }

        // x_aug, softmax(x_aug*y/10), x_attn
        float xa0 = xpw[bi + lane];
        float yv0 = ysw[lane];
        float z0  = (xa0 * yv0) / 10.0f;
        float xa1 = 0.f, z1 = -INFINITY;
        if (lane < 16) {
            xa1 = xpw[bi + lane + 64];
            float yv1 = ysw[lane + 64];
            z1 = (xa1 * yv1) / 10.0f;
        }
        float m = fmaxf(z0, z1);
        #pragma unroll
        for (int off = 32; off; off >>= 1) m = fmaxf(m, __shfl_xor(m, off));
        float e0 = expf(z0 - m);
        float e1 = (lane < 16) ? expf(z1 - m) : 0.f;
        float es = e0 + e1;
        #pragma unroll
        for (int off = 32; off; off >>= 1) es += __shfl_xor(es, off);
        float inv = 1.0f / es;

        // write bf16 A-tile row straight to LDS; lanes 16..31 zero the K-pad [80,96)
        Abf[lrow][lane] = f2bf(xa0 * (e0 * inv));
        ushort_t a64 = 0;
        if (lane < 16) a64 = f2bf(xa1 * (e1 * inv));
        if (lane < 32) Abf[lrow][lane + 64] = a64;
        __syncthreads();   // Abf visible; xp scratch free for reuse next iter / W stage
    }

    // ---------------- Phase B: stage W (overwrites phase-A scratch) ----------------
    // 512 cols x 80 fp32 = 10240 float4; 20 per thread, coalesced
    #pragma unroll
    for (int q = 0; q < 20; ++q) {
        int idx = q * 512 + tid;
        int r   = idx / 20;
        int kp  = (idx % 20) * 4;
        float4 wv4 = *(const float4*)(wmat + (size_t)r * IDIM + kp);
        ushort4v wb = { f2bf(wv4.x), f2bf(wv4.y), f2bf(wv4.z), f2bf(wv4.w) };
        *(ushort4v*)&Wbf[r][kp] = wb;
    }
    {   // zero the K-pad region [80, 96) — one row per thread
        ushort4v z = {0, 0, 0, 0};
        *(ushort4v*)&Wbf[tid][80] = z; *(ushort4v*)&Wbf[tid][84] = z;
        *(ushort4v*)&Wbf[tid][88] = z; *(ushort4v*)&Wbf[tid][92] = z;
    }
    __syncthreads();

    // ---------------- MFMA: 32 rows x 512 cols, K=96 ----------------
    const int rg   = wv & 1;          // row-group: rows [16*rg, 16*rg+16)
    const int cg   = wv >> 1;         // col-group: cols [128*cg, 128*cg+128)
    const int m    = lane & 15;
    const int q4   = lane >> 4;       // quad

    short8 af[3];
    #pragma unroll
    for (int kt = 0; kt < 3; ++kt)
        af[kt] = *(const short8*)&Abf[16 * rg + m][q4 * 8 + kt * 32];

    floatx4 acc[8];
    #pragma unroll
    for (int ct = 0; ct < 8; ++ct) acc[ct] = (floatx4){0.f, 0.f, 0.f, 0.f};

    #pragma unroll
    for (int ct = 0; ct < 8; ++ct) {
        #pragma unroll
        for (int kt = 0; kt < 3; ++kt) {
            short8 bf = *(const short8*)&Wbf[cg * 128 + ct * 16 + m][q4 * 8 + kt * 32];
            acc[ct] = __builtin_amdgcn_mfma_f32_16x16x32_bf16(af[kt], bf, acc[ct], 0, 0, 0);
        }
    }

    // epilogue: C/D layout col=lane&15, row=quad*4+reg  (m89/m91-verified)
    #pragma unroll
    for (int ct = 0; ct < 8; ++ct) {
        int col = cg * 128 + ct * 16 + m;
        float bsv = bias[col];
        int row0 = rb + 16 * rg + q4 * 4;
        #pragma unroll
        for (int i = 0; i < 4; ++i)
            out[(size_t)(row0 + i) * HDIM + col] = acc[ct][i] + bsv;
    }
}

extern "C" void kernel_launch(void* const* d_in, const int* in_sizes, int n_in,
                              void* d_out, int out_size, void* d_ws, size_t ws_size,
                              hipStream_t stream) {
    const float* x  = (const float*)d_in[0];
    const float* y  = (const float*)d_in[1];
    const float* wm = (const float*)d_in[2];
    const float* bs = (const float*)d_in[3];
    float* out = (float*)d_out;
    (void)d_ws; (void)ws_size;   // workspace deliberately unused

    k_fused<<<dim3(NBLK), 512, 0, stream>>>(x, y, wm, bs, out);
}

// Round 3
// 84.121 us; speedup vs baseline: 1.1114x; 1.1114x over previous
//
#include <hip/hip_runtime.h>
#include <math.h>

#define BT    8192      // B*T = 16*512
#define IDIM  80
#define HDIM  512
#define SPAN  159       // 2*IDIM-1
#define SXQ   84        // float4 slots per wave slot: 336 floats, zero-padded
#define LDK   104       // LDS row stride in halfwords (bank-friendly, 16B-aligned)

typedef unsigned short ushort_t;
typedef __attribute__((ext_vector_type(8))) short short8;
typedef __attribute__((ext_vector_type(4))) float floatx4;
typedef __attribute__((ext_vector_type(4))) unsigned short ushort4v;

__device__ inline ushort_t f2bf(float f) {
    union { float f; unsigned int i; } v; v.f = f;
    unsigned int x = v.i;
    return (ushort_t)((x + 0x7fffu + ((x >> 16) & 1u)) >> 16);   // RNE
}

__device__ inline float rlane(float v, int l) {
    return __uint_as_float((unsigned int)__builtin_amdgcn_readlane((int)__float_as_uint(v), l));
}

// ---------------- Kernel 1: sliding cosine-sim argmax + softmax ----------------
// One wave per (b,t) row; 4 rows per 256-thread block.
// Inner loop: lane l owns shifts 4l..4l+3 so each K-step needs ONE aligned
// ds_read_b128 (sliding 8-value window) instead of 3 scalar ds_read_b32.
// LDS-pipe instrs per row: 240 b32 -> 20 b128 (~6x less LDS-pipe time).
__global__ __launch_bounds__(256) void k_attn(const float* __restrict__ x,
                                              const float* __restrict__ y,
                                              ushort_t* __restrict__ xattn) {
    __shared__ __align__(16) float sx[4][SXQ * 4];   // sx[w][79+j] = x[j], zeros elsewhere
    __shared__ float ysm[4][IDIM];
    const int w    = threadIdx.x >> 6;
    const int lane = threadIdx.x & 63;
    const int row  = blockIdx.x * 4 + w;
    const float* xr = x + (size_t)row * IDIM;
    const float* yr = y + (size_t)row * IDIM;
    float* sxw = sx[w];

    // zero the padded-x slot (336 floats as float4)
    {
        float4 z = make_float4(0.f, 0.f, 0.f, 0.f);
        *(float4*)&sxw[lane * 4] = z;
        if (lane < SXQ - 64) *(float4*)&sxw[(lane + 64) * 4] = z;
    }
    float4 yv4 = make_float4(0.f, 0.f, 0.f, 0.f);
    float yy = 0.f;
    if (lane < 20) {
        float4 xv = *(const float4*)(xr + lane * 4);
        yv4       = *(const float4*)(yr + lane * 4);
        int b = 79 + lane * 4;
        sxw[b + 0] = xv.x; sxw[b + 1] = xv.y;
        sxw[b + 2] = xv.z; sxw[b + 3] = xv.w;
        int c = lane * 4;
        ysm[w][c + 0] = yv4.x; ysm[w][c + 1] = yv4.y;
        ysm[w][c + 2] = yv4.z; ysm[w][c + 3] = yv4.w;
        yy = yv4.x * yv4.x + yv4.y * yv4.y + yv4.z * yv4.z + yv4.w * yv4.w;
    }
    __syncthreads();
    #pragma unroll
    for (int off = 32; off; off >>= 1) yy += __shfl_xor(yy, off);

    // sliding dot + norm: shifts s = 4*lane + c (c=0..3), K-step of 4 y values.
    // window values for all 4 shifts at step i4: sx[4*lane + 4*i4 .. +7]
    //   = float4 cur (=sx4[lane+i4]) and nxt (=sx4[lane+i4+1]); nxt reused as cur.
    float d0 = 0.f, d1 = 0.f, d2 = 0.f, d3 = 0.f;
    float n0 = 0.f, n1 = 0.f, n2 = 0.f, n3 = 0.f;
    float4 cur = *(const float4*)&sxw[4 * lane];
    #pragma unroll
    for (int i4 = 0; i4 < 20; ++i4) {
        float4 nxt = *(const float4*)&sxw[4 * (lane + i4 + 1)];
        float y0 = rlane(yv4.x, i4);
        float y1 = rlane(yv4.y, i4);
        float y2 = rlane(yv4.z, i4);
        float y3 = rlane(yv4.w, i4);
        float v0 = cur.x, v1 = cur.y, v2 = cur.z, v3 = cur.w;
        float v4 = nxt.x, v5 = nxt.y, v6 = nxt.z;
        d0 = fmaf(y3, v3, fmaf(y2, v2, fmaf(y1, v1, fmaf(y0, v0, d0))));
        d1 = fmaf(y3, v4, fmaf(y2, v3, fmaf(y1, v2, fmaf(y0, v1, d1))));
        d2 = fmaf(y3, v5, fmaf(y2, v4, fmaf(y1, v3, fmaf(y0, v2, d2))));
        d3 = fmaf(y3, v6, fmaf(y2, v5, fmaf(y1, v4, fmaf(y0, v3, d3))));
        n0 = fmaf(v3, v3, fmaf(v2, v2, fmaf(v1, v1, fmaf(v0, v0, n0))));
        n1 = fmaf(v4, v4, fmaf(v3, v3, fmaf(v2, v2, fmaf(v1, v1, n1))));
        n2 = fmaf(v5, v5, fmaf(v4, v4, fmaf(v3, v3, fmaf(v2, v2, n2))));
        n3 = fmaf(v6, v6, fmaf(v5, v5, fmaf(v4, v4, fmaf(v3, v3, n3))));
        cur = nxt;
    }
    const int sbase = 4 * lane;
    float s0 = (n0 > 0.f) ? d0 / sqrtf(yy * n0) : 0.f;
    float s1 = (n1 > 0.f) ? d1 / sqrtf(yy * n1) : 0.f;
    float s2 = (n2 > 0.f) ? d2 / sqrtf(yy * n2) : 0.f;
    float s3 = (n3 > 0.f) ? d3 / sqrtf(yy * n3) : 0.f;
    if (sbase + 0 > SPAN - 1) s0 = -INFINITY;
    if (sbase + 1 > SPAN - 1) s1 = -INFINITY;
    if (sbase + 2 > SPAN - 1) s2 = -INFINITY;
    if (sbase + 3 > SPAN - 1) s3 = -INFINITY;

    // argmax, smallest index on ties (ascending c with strict > keeps smallest)
    float bv = s0; int bi = sbase;
    if (s1 > bv) { bv = s1; bi = sbase + 1; }
    if (s2 > bv) { bv = s2; bi = sbase + 2; }
    if (s3 > bv) { bv = s3; bi = sbase + 3; }
    #pragma unroll
    for (int off = 32; off; off >>= 1) {
        float ov = __shfl_xor(bv, off);
        int   oi = __shfl_xor(bi, off);
        if (ov > bv || (ov == bv && oi < bi)) { bv = ov; bi = oi; }
    }

    // x_aug, softmax(x_aug*y/10), x_attn
    const float* ysw = ysm[w];
    float xa0 = sxw[bi + lane];
    float yv0 = ysw[lane];
    float z0  = (xa0 * yv0) / 10.0f;
    float xa1 = 0.f, z1 = -INFINITY;
    if (lane < 16) {
        xa1 = sxw[bi + lane + 64];
        float yv1 = ysw[lane + 64];
        z1 = (xa1 * yv1) / 10.0f;
    }
    float m = fmaxf(z0, z1);
    #pragma unroll
    for (int off = 32; off; off >>= 1) m = fmaxf(m, __shfl_xor(m, off));
    float e0 = expf(z0 - m);
    float e1 = (lane < 16) ? expf(z1 - m) : 0.f;
    float es = e0 + e1;
    #pragma unroll
    for (int off = 32; off; off >>= 1) es += __shfl_xor(es, off);
    float inv = 1.0f / es;

    ushort_t* orow = xattn + (size_t)row * IDIM;
    orow[lane] = f2bf(xa0 * (e0 * inv));
    if (lane < 16) orow[lane + 64] = f2bf(xa1 * (e1 * inv));
}

// ------------- Kernel 2: h = x_attn @ W^T + b  via bf16 MFMA 16x16x32 -------------
// Unchanged from the 84.1 us baseline (isolating the k_attn change).
__global__ __launch_bounds__(256) void k_gemm_mfma(const ushort_t* __restrict__ xattn,
                                                   const float* __restrict__ wmat,
                                                   const float* __restrict__ bias,
                                                   float* __restrict__ out) {
    __shared__ __align__(16) ushort_t Abf[64][LDK];
    __shared__ __align__(16) ushort_t Wbf[64][LDK];
    const int tid = threadIdx.x;
    const int rb  = blockIdx.x * 64;
    const int cb  = blockIdx.y * 64;

    // zero the K-pad region [80, 96)
    if (tid < 64) {
        ushort4v z = {0, 0, 0, 0};
        *(ushort4v*)&Abf[tid][80] = z; *(ushort4v*)&Abf[tid][84] = z;
        *(ushort4v*)&Abf[tid][88] = z; *(ushort4v*)&Abf[tid][92] = z;
        *(ushort4v*)&Wbf[tid][80] = z; *(ushort4v*)&Wbf[tid][84] = z;
        *(ushort4v*)&Wbf[tid][88] = z; *(ushort4v*)&Wbf[tid][92] = z;
    }
    // stage A tile: 64 rows x 80 bf16 = 640 uint4 (8 bf16 each), coalesced
    #pragma unroll
    for (int q = 0; q < 3; ++q) {
        int idx = q * 256 + tid;
        if (idx < 640) {
            int r  = idx / 10;           // 10 uint4 per row
            int kp = (idx % 10) * 8;
            uint4 v = *(const uint4*)(xattn + (size_t)(rb + r) * IDIM + kp);
            *(uint4*)&Abf[r][kp] = v;
        }
    }
    // stage + convert W tile: 64 cols x 80 fp32 = 1280 float4
    #pragma unroll
    for (int q = 0; q < 5; ++q) {
        int idx = q * 256 + tid;
        int r   = idx / 20;
        int kp  = (idx % 20) * 4;
        float4 wv = *(const float4*)(wmat + (size_t)(cb + r) * IDIM + kp);
        ushort4v wb = { f2bf(wv.x), f2bf(wv.y), f2bf(wv.z), f2bf(wv.w) };
        *(ushort4v*)&Wbf[r][kp] = wb;
    }
    __syncthreads();

    const int wv   = tid >> 6;        // wave 0..3 -> rows [16*wv, 16*wv+16)
    const int lane = tid & 63;
    const int m    = lane & 15;
    const int q4   = lane >> 4;       // quad

    // A fragments: 3 K-steps of 32
    short8 af[3];
    #pragma unroll
    for (int kt = 0; kt < 3; ++kt)
        af[kt] = *(const short8*)&Abf[16 * wv + m][q4 * 8 + kt * 32];

    floatx4 acc[4] = {{0.f,0.f,0.f,0.f}, {0.f,0.f,0.f,0.f},
                      {0.f,0.f,0.f,0.f}, {0.f,0.f,0.f,0.f}};
    #pragma unroll
    for (int ct = 0; ct < 4; ++ct) {
        #pragma unroll
        for (int kt = 0; kt < 3; ++kt) {
            short8 bf = *(const short8*)&Wbf[ct * 16 + m][q4 * 8 + kt * 32];
            acc[ct] = __builtin_amdgcn_mfma_f32_16x16x32_bf16(af[kt], bf, acc[ct], 0, 0, 0);
        }
    }

    // epilogue: C/D layout col=lane&15, row=quad*4+reg  (m89/m91-verified)
    #pragma unroll
    for (int ct = 0; ct < 4; ++ct) {
        int col = cb + ct * 16 + m;
        float bsv = bias[col];
        int row0 = rb + 16 * wv + q4 * 4;
        #pragma unroll
        for (int i = 0; i < 4; ++i)
            out[(size_t)(row0 + i) * HDIM + col] = acc[ct][i] + bsv;
    }
}

extern "C" void kernel_launch(void* const* d_in, const int* in_sizes, int n_in,
                              void* d_out, int out_size, void* d_ws, size_t ws_size,
                              hipStream_t stream) {
    const float* x  = (const float*)d_in[0];
    const float* y  = (const float*)d_in[1];
    const float* wm = (const float*)d_in[2];
    const float* bs = (const float*)d_in[3];
    float* out = (float*)d_out;
    ushort_t* xattn = (ushort_t*)d_ws;   // BT*IDIM*2 = 1.31 MB scratch (bf16)

    k_attn<<<dim3(BT / 4), 256, 0, stream>>>(x, y, xattn);
    k_gemm_mfma<<<dim3(BT / 64, HDIM / 64), 256, 0, stream>>>(xattn, wm, bs, out);
}